// Round 1
// baseline (398.437 us; speedup 1.0000x reference)
//
#include <hip/hip_runtime.h>

#define CAP 4096   // candidate capacity per query; expected ~278, >200 sigma safe

__global__ __launch_bounds__(256) void cylgroup_kernel(
    const float* __restrict__ radius_p,
    const float* __restrict__ hmin_p,
    const float* __restrict__ hmax_p,
    const float* __restrict__ xyz,      // (B, N, 3)
    const float* __restrict__ new_xyz,  // (B, P, 3)
    const float* __restrict__ rot,      // (B, P, 3, 3)
    const float* __restrict__ feat,     // (B, C, N)
    float* __restrict__ out)            // (B, 3+C, P, S)
{
    const int N = 16384, P = 1024, C = 64, S = 32, OC = 3 + C;
    const int bp  = blockIdx.x;
    const int b   = bp >> 10;          // P = 1024
    const int p   = bp & (P - 1);
    const int tid = threadIdx.x;

    __shared__ double cr2[CAP];
    __shared__ int    cn[CAP];
    __shared__ int    cnt;
    __shared__ int    sel[32];
    __shared__ double wmin_r2[4];
    __shared__ int    wmin_n[4];
    __shared__ int    bbn;

    if (tid == 0) cnt = 0;
    __syncthreads();

    const double radius = (double)radius_p[0];
    const double hmin   = (double)hmin_p[0];
    const double hmax   = (double)hmax_p[0];
    const double rad2   = radius * radius;

    const float* nx = new_xyz + (size_t)bp * 3;
    const double cx = nx[0], cy = nx[1], cz = nx[2];
    const float* rp = rot + (size_t)bp * 9;
    const double r00 = rp[0], r01 = rp[1], r02 = rp[2];
    const double r10 = rp[3], r11 = rp[4], r12 = rp[5];
    const double r20 = rp[6], r21 = rp[7], r22 = rp[8];

    const float* xb = xyz + (size_t)b * N * 3;

    // ---- Phase 1: scan all points, collect in-cylinder candidates ----
    for (int n = tid; n < N; n += 256) {
        double dx = (double)xb[n * 3 + 0] - cx;
        double dy = (double)xb[n * 3 + 1] - cy;
        double dz = (double)xb[n * 3 + 2] - cz;
        // local = diff @ rot  (local[d] = sum_c diff[c] * rot[c][d])
        double x = dx * r00 + dy * r10 + dz * r20;
        double y = dx * r01 + dy * r11 + dz * r21;
        double z = dx * r02 + dy * r12 + dz * r22;
        double r2 = y * y + z * z;
        if (x >= hmin && x <= hmax && r2 < rad2) {
            int slot = atomicAdd(&cnt, 1);
            if (slot < CAP) { cr2[slot] = r2; cn[slot] = n; }
        }
    }
    __syncthreads();

    int M    = min(cnt, CAP);
    int nsel = min(M, S);

    // ---- Phase 2: 32 rounds of block-argmin (r2 asc, index asc tiebreak) ----
    for (int round = 0; round < nsel; ++round) {
        double br2 = 1.0e300;
        int    bn  = 0x7fffffff;
        for (int j = tid; j < M; j += 256) {
            double v = cr2[j];
            int    n = cn[j];
            if (v < br2 || (v == br2 && n < bn)) { br2 = v; bn = n; }
        }
        // wave (64-lane) butterfly reduce
        for (int off = 32; off > 0; off >>= 1) {
            double o2 = __shfl_down(br2, off);
            int    on = __shfl_down(bn, off);
            if (o2 < br2 || (o2 == br2 && on < bn)) { br2 = o2; bn = on; }
        }
        int w = tid >> 6;
        if ((tid & 63) == 0) { wmin_r2[w] = br2; wmin_n[w] = bn; }
        __syncthreads();
        if (tid == 0) {
            double m  = wmin_r2[0];
            int    mn = wmin_n[0];
            for (int i = 1; i < 4; ++i) {
                if (wmin_r2[i] < m || (wmin_r2[i] == m && wmin_n[i] < mn)) {
                    m = wmin_r2[i]; mn = wmin_n[i];
                }
            }
            sel[round] = mn;
            bbn = mn;
        }
        __syncthreads();
        int win = bbn;
        for (int j = tid; j < M; j += 256) {
            if (cn[j] == win) cr2[j] = 1.0e300;   // remove winner
        }
        __syncthreads();
    }

    // fill invalid slots with first index (or 0 if no valid point at all)
    if (tid < S && tid >= nsel) sel[tid] = (nsel > 0) ? sel[0] : 0;
    __syncthreads();

    // ---- Phase 3a: grouped_xyz (rotated local coords of selected points) ----
    if (tid < S) {
        int n = sel[tid];
        double dx = (double)xb[n * 3 + 0] - cx;
        double dy = (double)xb[n * 3 + 1] - cy;
        double dz = (double)xb[n * 3 + 2] - cz;
        float x = (float)(dx * r00 + dy * r10 + dz * r20);
        float y = (float)(dx * r01 + dy * r11 + dz * r21);
        float z = (float)(dx * r02 + dy * r12 + dz * r22);
        float* o = out + (((size_t)b * OC + 0) * P + p) * S + tid;
        o[0 * (size_t)P * S] = x;
        o[1 * (size_t)P * S] = y;
        o[2 * (size_t)P * S] = z;
    }

    // ---- Phase 3b: grouped_features gather ----
    const float* fb = feat + (size_t)b * C * N;
    float* ob = out + (((size_t)b * OC + 3) * P + p) * S;
    for (int e = tid; e < C * S; e += 256) {
        int c = e >> 5;       // S = 32
        int s = e & 31;
        ob[(size_t)c * P * S + s] = fb[(size_t)c * N + sel[s]];
    }
}

extern "C" void kernel_launch(void* const* d_in, const int* in_sizes, int n_in,
                              void* d_out, int out_size, void* d_ws, size_t ws_size,
                              hipStream_t stream) {
    const float* radius  = (const float*)d_in[0];
    const float* hmin    = (const float*)d_in[1];
    const float* hmax    = (const float*)d_in[2];
    // d_in[3] = nsample (int, fixed 32) — compile-time constant here
    const float* xyz     = (const float*)d_in[4];
    const float* new_xyz = (const float*)d_in[5];
    const float* rot     = (const float*)d_in[6];
    const float* feat    = (const float*)d_in[7];
    float* out = (float*)d_out;

    dim3 grid(4096);   // B * P = 4 * 1024
    dim3 block(256);
    hipLaunchKernelGGL(cylgroup_kernel, grid, block, 0, stream,
                       radius, hmin, hmax, xyz, new_xyz, rot, feat, out);
}